// Round 6
// baseline (292.867 us; speedup 1.0000x reference)
//
#include <hip/hip_runtime.h>
#include <hip/hip_bf16.h>

// N=100000 nodes, E=1.6M edges (dst-sorted), IN_C=256, HID_C=128, OUT_C=256.
// f32 inputs; GEMMs run as bf16 MFMA with f32 accumulate.
// Pipeline: wprep -> [hist1, scan, scatter_keys, count] (atomic-free outdeg)
//           -> gemm1 -> rowptr -> gather -> gemm23 (fused).

typedef __attribute__((ext_vector_type(8))) short short8;
typedef __attribute__((ext_vector_type(4))) float f32x4;

static __device__ __forceinline__ float bf2f(unsigned int u16) {
    union { unsigned int i; float f; } c; c.i = u16 << 16; return c.f;
}
static __device__ __forceinline__ ushort f2bf(float f) {
    union { float f; unsigned int i; } c; c.f = f;
    unsigned int i = c.i;
    return (ushort)((i + 0x7FFFu + ((i >> 16) & 1u)) >> 16);   // RNE
}

constexpr int NCHUNK   = 256;   // edge chunks for bucket sort
constexpr int NBUK_MAX = 512;   // LDS array size (actual buckets = ceil(N/256))

// ---------------------------------------------------------------------------
// Bucket-sort-based out-degree (no global atomics).
// Stage 1: per-chunk LDS histogram over buckets (src>>8).
__global__ __launch_bounds__(256) void hist1_kernel(
    const int* __restrict__ src, int* __restrict__ M, int nE, int nBuk, int chunkSz)
{
    __shared__ int cnt[NBUK_MAX];
    int c = blockIdx.x, tid = threadIdx.x;
    for (int i = tid; i < nBuk; i += 256) cnt[i] = 0;
    __syncthreads();
    int e0 = c * chunkSz, e1 = min(e0 + chunkSz, nE);
    for (int e = e0 + tid; e < e1; e += 256)
        atomicAdd(&cnt[src[e] >> 8], 1);            // LDS atomic
    __syncthreads();
    for (int b = tid; b < nBuk; b += 256)
        M[c * nBuk + b] = cnt[b];
}

// Stage 2: M[c][b] -> absolute exclusive offsets; bucket_base[b] totals.
__global__ __launch_bounds__(512) void scan_kernel(
    int* __restrict__ M, int* __restrict__ bucket_base, int nBuk, int nChunk)
{
    __shared__ int tot[NBUK_MAX], base_l[NBUK_MAX];
    int b = threadIdx.x;
    if (b < nBuk) {
        int run = 0;
        for (int c = 0; c < nChunk; ++c) {
            int t = M[c * nBuk + b];
            M[c * nBuk + b] = run;
            run += t;
        }
        tot[b] = run;
    }
    __syncthreads();
    if (b == 0) {
        int base = 0;
        for (int i = 0; i < nBuk; ++i) {
            base_l[i] = base;
            bucket_base[i] = base;
            base += tot[i];
        }
        bucket_base[nBuk] = base;
    }
    __syncthreads();
    if (b < nBuk) {
        int add = base_l[b];
        for (int c = 0; c < nChunk; ++c) M[c * nBuk + b] += add;
    }
}

// Stage 3: scatter src keys into bucket-sorted order (LDS cursors).
__global__ __launch_bounds__(256) void scatter_keys_kernel(
    const int* __restrict__ src, const int* __restrict__ M,
    int* __restrict__ ss, int nE, int nBuk, int chunkSz)
{
    __shared__ int cur[NBUK_MAX];
    int c = blockIdx.x, tid = threadIdx.x;
    for (int i = tid; i < nBuk; i += 256) cur[i] = M[c * nBuk + i];
    __syncthreads();
    int e0 = c * chunkSz, e1 = min(e0 + chunkSz, nE);
    for (int e = e0 + tid; e < e1; e += 256) {
        int s = src[e];
        int pos = atomicAdd(&cur[s >> 8], 1);       // LDS atomic
        ss[pos] = s;
    }
}

// Stage 4: one block per bucket; LDS 256-bin histogram; plain stores.
__global__ __launch_bounds__(256) void count_kernel(
    const int* __restrict__ ss, const int* __restrict__ bucket_base,
    int* __restrict__ outdeg, int N)
{
    __shared__ int hist[256];
    int b = blockIdx.x, tid = threadIdx.x;
    hist[tid] = 0;
    __syncthreads();
    int e0 = bucket_base[b], e1 = bucket_base[b + 1];
    for (int e = e0 + tid; e < e1; e += 256)
        atomicAdd(&hist[ss[e] & 255], 1);           // LDS atomic
    __syncthreads();
    int n = b * 256 + tid;
    if (n < N) outdeg[n] = hist[tid];
}

// ---------------------------------------------------------------------------
// row_ptr[n] = lower_bound(dst, n); dst is sorted.
__global__ __launch_bounds__(256) void rowptr_kernel(
    const int* __restrict__ dst, int* __restrict__ row_ptr, int nE, int N)
{
    int e = blockIdx.x * 256 + threadIdx.x;
    if (e >= nE) return;
    int d = dst[e];
    if (e == 0) {
        for (int n = 0; n <= d; ++n) row_ptr[n] = 0;
    } else {
        int p = dst[e - 1];
        for (int n = p + 1; n <= d; ++n) row_ptr[n] = e;
    }
    if (e == nE - 1) {
        for (int n = d + 1; n <= N; ++n) row_ptr[n] = nE;
    }
}

// ---------------------------------------------------------------------------
// Weight prep: W_convT[o][k] = bf16(W_conv[k][o]); W1b, W2b = bf16 copies.
__global__ __launch_bounds__(256) void wprep_kernel(
    const float* __restrict__ Wc, const float* __restrict__ W1,
    const float* __restrict__ W2, ushort* __restrict__ WcT,
    ushort* __restrict__ W1b, ushort* __restrict__ W2b)
{
    int i = blockIdx.x * 256 + threadIdx.x;
    if (i < 128 * 256) {
        int o = i >> 8, k = i & 255;
        WcT[o * 256 + k] = f2bf(Wc[k * 128 + o]);
    } else if (i < 128 * 256 + 128 * 128) {
        int j = i - 128 * 256;
        W1b[j] = f2bf(W1[j]);
    } else if (i < 128 * 256 + 128 * 128 + 256 * 128) {
        int j = i - 128 * 256 - 128 * 128;
        W2b[j] = f2bf(W2[j]);
    }
}

// ---------------------------------------------------------------------------
// GEMM1: h1u[64 rows x 128 cols per block] = bf16[x @ W_conv] (unscaled).
__global__ __launch_bounds__(256) void gemm1_kernel(
    const float* __restrict__ A, const ushort* __restrict__ B,
    ushort* __restrict__ C, int nRows)
{
    __shared__ ushort As[64 * 64];    // 8 KB
    __shared__ ushort Bs[128 * 64];   // 16 KB

    const int tid  = threadIdx.x;
    const int lane = tid & 63;
    const int w    = tid >> 6;
    const int r    = lane & 15;
    const int q    = lane >> 4;
    const int row0 = blockIdx.x * 64;

    f32x4 acc[8];
#pragma unroll
    for (int t = 0; t < 8; ++t) acc[t] = (f32x4){0.f, 0.f, 0.f, 0.f};

    for (int k0 = 0; k0 < 256; k0 += 64) {
        __syncthreads();
#pragma unroll
        for (int s = 0; s < 2; ++s) {
            int idx = s * 256 + tid;
            int row = idx >> 3, kg = idx & 7;
            int g = row0 + row;
            float4 v0 = make_float4(0.f, 0.f, 0.f, 0.f), v1 = v0;
            if (g < nRows) {
                v0 = *(const float4*)&A[(size_t)g * 256 + k0 + kg * 8];
                v1 = *(const float4*)&A[(size_t)g * 256 + k0 + kg * 8 + 4];
            }
            ushort u[8];
            u[0] = f2bf(v0.x); u[1] = f2bf(v0.y); u[2] = f2bf(v0.z); u[3] = f2bf(v0.w);
            u[4] = f2bf(v1.x); u[5] = f2bf(v1.y); u[6] = f2bf(v1.z); u[7] = f2bf(v1.w);
            *(short8*)&As[row * 64 + ((kg ^ (row & 7)) * 8)] = *(const short8*)u;
        }
#pragma unroll
        for (int s = 0; s < 4; ++s) {
            int idx = s * 256 + tid;
            int col = idx >> 3, kg = idx & 7;
            *(short8*)&Bs[col * 64 + ((kg ^ (col & 7)) * 8)] =
                *(const short8*)&B[(size_t)col * 256 + k0 + kg * 8];
        }
        __syncthreads();

#pragma unroll
        for (int ks = 0; ks < 2; ++ks) {
            short8 af = *(const short8*)&As[(w * 16 + r) * 64 + (((ks * 4 + q) ^ (r & 7)) * 8)];
#pragma unroll
            for (int t = 0; t < 8; ++t) {
                short8 bf = *(const short8*)&Bs[(t * 16 + r) * 64 + (((ks * 4 + q) ^ (r & 7)) * 8)];
                acc[t] = __builtin_amdgcn_mfma_f32_16x16x32_bf16(af, bf, acc[t], 0, 0, 0);
            }
        }
    }

#pragma unroll
    for (int t = 0; t < 8; ++t) {
        int col = t * 16 + r;
#pragma unroll
        for (int reg = 0; reg < 4; ++reg) {
            int g = row0 + w * 16 + q * 4 + reg;
            if (g < nRows)
                C[(size_t)g * 128 + col] = f2bf(acc[t][reg]);
        }
    }
}

// ---------------------------------------------------------------------------
// CSR gather, 4 edges in flight per wave; per-edge scale rsqrt(outdeg[src]).
// Fuses rsqrt(indeg) + b_conv + ReLU; bf16 out.
__global__ __launch_bounds__(256) void gather_kernel(
    const ushort* __restrict__ h1, const int* __restrict__ src,
    const int* __restrict__ rp, const int* __restrict__ outdeg,
    const float* __restrict__ b_conv, ushort* __restrict__ h2, int N)
{
    int n = (blockIdx.x * 256 + threadIdx.x) >> 6;
    int lane = threadIdx.x & 63;
    if (n >= N) return;
    const int g = lane >> 4;
    const int c = lane & 15;
    int e0 = rp[n], e1 = rp[n + 1];

    float a[8];
#pragma unroll
    for (int j = 0; j < 8; ++j) a[j] = 0.f;

    int e = e0 + g;
    for (; e + 4 < e1; e += 8) {           // 2 edges in flight per lane
        int s0 = src[e], s1 = src[e + 4];
        float sc0 = rsqrtf((float)max(outdeg[s0], 1));
        float sc1 = rsqrtf((float)max(outdeg[s1], 1));
        short8 v0 = *(const short8*)&h1[(size_t)s0 * 128 + c * 8];
        short8 v1 = *(const short8*)&h1[(size_t)s1 * 128 + c * 8];
#pragma unroll
        for (int j = 0; j < 8; ++j)
            a[j] = fmaf(sc0, bf2f((unsigned short)v0[j]),
                        fmaf(sc1, bf2f((unsigned short)v1[j]), a[j]));
    }
    if (e < e1) {
        int s0 = src[e];
        float sc0 = rsqrtf((float)max(outdeg[s0], 1));
        short8 v0 = *(const short8*)&h1[(size_t)s0 * 128 + c * 8];
#pragma unroll
        for (int j = 0; j < 8; ++j)
            a[j] = fmaf(sc0, bf2f((unsigned short)v0[j]), a[j]);
    }

#pragma unroll
    for (int j = 0; j < 8; ++j) {
        a[j] += __shfl_xor(a[j], 16, 64);
        a[j] += __shfl_xor(a[j], 32, 64);
    }

    if (g == 0) {
        float sc = rsqrtf((float)max(e1 - e0, 1));
        ushort o[8];
#pragma unroll
        for (int j = 0; j < 8; ++j)
            o[j] = f2bf(fmaxf(fmaf(a[j], sc, b_conv[c * 8 + j]), 0.f));
        *(short8*)&h2[(size_t)n * 128 + c * 8] = *(const short8*)o;
    }
}

// ---------------------------------------------------------------------------
// Fused GEMM2+GEMM3: per 64-row block,
//   stage1: T = relu(h2 @ W1^T + b1)        [64 x 128] -> bf16 in LDS (Ts)
//   stage2: out = T @ W2^T + b2             [64 x 256] -> f32 global
// LDS: stage1 As[8K]+Bs[16K]; Ts aliases [0,16K); Bs2 at [16K,48K).
__global__ __launch_bounds__(256) void gemm23_kernel(
    const ushort* __restrict__ A, const ushort* __restrict__ W1b,
    const ushort* __restrict__ W2b, const float* __restrict__ b1,
    const float* __restrict__ b2, float* __restrict__ out, int nRows)
{
    __shared__ char lds_raw[49152];
    ushort* As  = (ushort*)lds_raw;             // [64][64]   stage1
    ushort* Bs  = (ushort*)(lds_raw + 8192);    // [128][64]  stage1
    ushort* Ts  = (ushort*)lds_raw;             // [64][128]  stage2 A
    ushort* Bs2 = (ushort*)(lds_raw + 16384);   // [256][64]  stage2 B

    const int tid  = threadIdx.x;
    const int lane = tid & 63;
    const int w    = tid >> 6;
    const int r    = lane & 15;
    const int q    = lane >> 4;
    const int row0 = blockIdx.x * 64;

    // ---------------- stage 1: h2 @ W1^T ----------------
    f32x4 acc1[8];
#pragma unroll
    for (int t = 0; t < 8; ++t) acc1[t] = (f32x4){0.f, 0.f, 0.f, 0.f};

    for (int k0 = 0; k0 < 128; k0 += 64) {
        __syncthreads();
#pragma unroll
        for (int s = 0; s < 2; ++s) {
            int idx = s * 256 + tid;
            int row = idx >> 3, kg = idx & 7;
            int g = row0 + row;
            short8 v = (short8){0, 0, 0, 0, 0, 0, 0, 0};
            if (g < nRows)
                v = *(const short8*)&A[(size_t)g * 128 + k0 + kg * 8];
            *(short8*)&As[row * 64 + ((kg ^ (row & 7)) * 8)] = v;
        }
#pragma unroll
        for (int s = 0; s < 4; ++s) {
            int idx = s * 256 + tid;
            int col = idx >> 3, kg = idx & 7;
            *(short8*)&Bs[col * 64 + ((kg ^ (col & 7)) * 8)] =
                *(const short8*)&W1b[(size_t)col * 128 + k0 + kg * 8];
        }
        __syncthreads();

#pragma unroll
        for (int ks = 0; ks < 2; ++ks) {
            short8 af = *(const short8*)&As[(w * 16 + r) * 64 + (((ks * 4 + q) ^ (r & 7)) * 8)];
#pragma unroll
            for (int t = 0; t < 8; ++t) {
                short8 bf = *(const short8*)&Bs[(t * 16 + r) * 64 + (((ks * 4 + q) ^ (r & 7)) * 8)];
                acc1[t] = __builtin_amdgcn_mfma_f32_16x16x32_bf16(af, bf, acc1[t], 0, 0, 0);
            }
        }
    }

    // T = relu(acc1 + b1) -> Ts (bf16, swizzled [64][128])
    __syncthreads();
#pragma unroll
    for (int t = 0; t < 8; ++t) {
        int col = t * 16 + r;
        float bo = b1[col];
        int slot = col >> 3;
#pragma unroll
        for (int reg = 0; reg < 4; ++reg) {
            int row = w * 16 + q * 4 + reg;
            float v = fmaxf(acc1[t][reg] + bo, 0.f);
            Ts[row * 128 + ((slot ^ (row & 7)) << 3) + (col & 7)] = f2bf(v);
        }
    }

    // ---------------- stage 2: T @ W2^T ----------------
    f32x4 acc2[16];
#pragma unroll
    for (int t = 0; t < 16; ++t) acc2[t] = (f32x4){0.f, 0.f, 0.f, 0.f};

    for (int k0 = 0; k0 < 128; k0 += 64) {
        __syncthreads();
#pragma unroll
        for (int s = 0; s < 8; ++s) {
            int idx = s * 256 + tid;         // 0..2047
            int col = idx >> 3, kg = idx & 7;
            *(short8*)&Bs2[col * 64 + ((kg ^ (col & 7)) * 8)] =
                *(const short8*)&W2b[(size_t)col * 128 + k0 + kg * 8];
        }
        __syncthreads();

#pragma unroll
        for (int ks = 0; ks < 2; ++ks) {
            int slot = (k0 >> 3) + ks * 4 + q;       // 0..15 within Ts row
            short8 af = *(const short8*)&Ts[(w * 16 + r) * 128 + ((slot ^ (r & 7)) * 8)];
#pragma unroll
            for (int t = 0; t < 16; ++t) {
                short8 bf = *(const short8*)&Bs2[(t * 16 + r) * 64 + (((ks * 4 + q) ^ (r & 7)) * 8)];
                acc2[t] = __builtin_amdgcn_mfma_f32_16x16x32_bf16(af, bf, acc2[t], 0, 0, 0);
            }
        }
    }

    // epilogue: f32 out + b2
#pragma unroll
    for (int t = 0; t < 16; ++t) {
        int col = t * 16 + r;
        float bo = b2[col];
#pragma unroll
        for (int reg = 0; reg < 4; ++reg) {
            int g = row0 + w * 16 + q * 4 + reg;
            if (g < nRows)
                out[(size_t)g * 256 + col] = acc2[t][reg] + bo;
        }
    }
}

// ---------------------------------------------------------------------------
extern "C" void kernel_launch(void* const* d_in, const int* in_sizes, int n_in,
                              void* d_out, int out_size, void* d_ws, size_t ws_size,
                              hipStream_t stream)
{
    const float* x      = (const float*)d_in[0];
    const int*   src    = (const int*)d_in[1];
    const int*   dst    = (const int*)d_in[2];
    const float* W_conv = (const float*)d_in[3];
    const float* b_conv = (const float*)d_in[4];
    const float* W1     = (const float*)d_in[5];
    const float* b1     = (const float*)d_in[6];
    const float* W2     = (const float*)d_in[7];
    const float* b2     = (const float*)d_in[8];
    float* out = (float*)d_out;

    const int N  = in_sizes[0] / 256;   // 100000
    const int nE = in_sizes[1];         // 1600000

    const int nBuk    = (N + 255) >> 8;                 // 391
    const int chunkSz = (nE + NCHUNK - 1) / NCHUNK;     // 6250

    // ws layout (ushort units for bf16 region, then ints):
    // h1 [N*128] | h2 [N*128] | WcT [128*256] | W1b [128*128] | W2b [256*128]
    // | outdeg [N] | rp [N+1] | bucket_base [nBuk+1] | M [NCHUNK*nBuk] | ss [nE]
    ushort* h1  = (ushort*)d_ws;
    ushort* h2  = h1 + (size_t)N * 128;
    ushort* WcT = h2 + (size_t)N * 128;
    ushort* W1b = WcT + 128 * 256;
    ushort* W2b = W1b + 128 * 128;
    int* outdeg = (int*)(W2b + 256 * 128);
    int* rp     = outdeg + N;
    int* bb     = rp + (N + 1);
    int* M      = bb + (nBuk + 1);
    int* ss     = M + NCHUNK * nBuk;

    wprep_kernel<<<(128 * 256 + 128 * 128 + 256 * 128 + 255) / 256, 256, 0, stream>>>(
        W_conv, W1, W2, WcT, W1b, W2b);

    // ---- atomic-free out-degree (bucket sort) ----
    hist1_kernel<<<NCHUNK, 256, 0, stream>>>(src, M, nE, nBuk, chunkSz);
    scan_kernel<<<1, 512, 0, stream>>>(M, bb, nBuk, NCHUNK);
    scatter_keys_kernel<<<NCHUNK, 256, 0, stream>>>(src, M, ss, nE, nBuk, chunkSz);
    count_kernel<<<nBuk, 256, 0, stream>>>(ss, bb, outdeg, N);

    const int nBlocks = (N + 63) / 64;   // 1563
    // h1 = bf16[x @ W_conv]  (unscaled)
    gemm1_kernel<<<nBlocks, 256, 0, stream>>>(x, WcT, h1, N);

    rowptr_kernel<<<(nE + 255) / 256, 256, 0, stream>>>(dst, rp, nE, N);

    // h2 = bf16[relu( (sum_e rsqrt(outdeg[src])*h1[src]) * rsqrt(indeg) + b_conv )]
    gather_kernel<<<(N * 64 + 255) / 256, 256, 0, stream>>>(
        h1, src, rp, outdeg, b_conv, h2, N);

    // out = relu(h2 @ W1^T + b1) @ W2^T + b2   (single fused kernel)
    gemm23_kernel<<<nBlocks, 256, 0, stream>>>(h2, W1b, W2b, b1, b2, out, N);
}

// Round 7
// 203.700 us; speedup vs baseline: 1.4377x; 1.4377x over previous
//
#include <hip/hip_runtime.h>
#include <hip/hip_bf16.h>

// N=100000 nodes, E=1.6M edges (dst-sorted), IN_C=256, HID_C=128, OUT_C=256.
// f32 inputs; GEMMs run as bf16 MFMA with f32 accumulate.
// Pipeline: wprep -> [hist1, scanA, scanB, scatter_keys, count] (atomic-free
//           outdeg) -> gemm1 -> rowptr -> gather -> gemm23 (fused).

typedef __attribute__((ext_vector_type(8))) short short8;
typedef __attribute__((ext_vector_type(4))) float f32x4;

static __device__ __forceinline__ float bf2f(unsigned int u16) {
    union { unsigned int i; float f; } c; c.i = u16 << 16; return c.f;
}
static __device__ __forceinline__ ushort f2bf(float f) {
    union { float f; unsigned int i; } c; c.f = f;
    unsigned int i = c.i;
    return (ushort)((i + 0x7FFFu + ((i >> 16) & 1u)) >> 16);   // RNE
}

constexpr int NCHUNK   = 256;   // edge chunks for bucket sort
constexpr int NBUK_MAX = 512;   // LDS array bound (actual buckets = ceil(N/256))

// ---------------------------------------------------------------------------
// Bucket-sort-based out-degree (no global atomics).
// M layout: [nBuk][NCHUNK] (bucket-major, contiguous per bucket).
// Stage 1: per-chunk LDS histogram over buckets (src>>8).
__global__ __launch_bounds__(256) void hist1_kernel(
    const int* __restrict__ src, int* __restrict__ M, int nE, int nBuk, int chunkSz)
{
    __shared__ int cnt[NBUK_MAX];
    int c = blockIdx.x, tid = threadIdx.x;
    for (int i = tid; i < nBuk; i += 256) cnt[i] = 0;
    __syncthreads();
    int e0 = c * chunkSz, e1 = min(e0 + chunkSz, nE);
    for (int e = e0 + tid; e < e1; e += 256)
        atomicAdd(&cnt[src[e] >> 8], 1);            // LDS atomic
    __syncthreads();
    for (int b = tid; b < nBuk; b += 256)
        M[b * NCHUNK + c] = cnt[b];
}

// Stage 2a: per-bucket exclusive scan over its 256 chunk counts (one block
// per bucket, Hillis-Steele in LDS); emits bucket totals.
__global__ __launch_bounds__(256) void scanA_kernel(
    int* __restrict__ M, int* __restrict__ tot)
{
    __shared__ int buf[2][NCHUNK];
    int b = blockIdx.x, tid = threadIdx.x;
    int v = M[b * NCHUNK + tid];
    buf[0][tid] = v;
    __syncthreads();
    int pi = 0;
#pragma unroll
    for (int off = 1; off < NCHUNK; off <<= 1) {
        int t = buf[pi][tid];
        if (tid >= off) t += buf[pi][tid - off];
        buf[pi ^ 1][tid] = t;
        __syncthreads();
        pi ^= 1;
    }
    int incl = buf[pi][tid];
    M[b * NCHUNK + tid] = incl - v;                 // exclusive
    if (tid == NCHUNK - 1) tot[b] = incl;
}

// Stage 2b: exclusive scan of bucket totals -> bucket_base[0..nBuk].
__global__ __launch_bounds__(512) void scanB_kernel(
    const int* __restrict__ tot, int* __restrict__ bucket_base, int nBuk)
{
    __shared__ int t_l[NBUK_MAX], base_l[NBUK_MAX + 1];
    int tid = threadIdx.x;
    if (tid < nBuk) t_l[tid] = tot[tid];
    __syncthreads();
    if (tid == 0) {
        int base = 0;
        for (int i = 0; i < nBuk; ++i) { base_l[i] = base; base += t_l[i]; }
        base_l[nBuk] = base;
    }
    __syncthreads();
    if (tid <= nBuk) bucket_base[tid] = base_l[tid];
}

// Stage 3: scatter src keys into bucket-sorted order (LDS cursors).
__global__ __launch_bounds__(256) void scatter_keys_kernel(
    const int* __restrict__ src, const int* __restrict__ M,
    const int* __restrict__ bucket_base, int* __restrict__ ss,
    int nE, int nBuk, int chunkSz)
{
    __shared__ int cur[NBUK_MAX];
    int c = blockIdx.x, tid = threadIdx.x;
    for (int i = tid; i < nBuk; i += 256)
        cur[i] = M[i * NCHUNK + c] + bucket_base[i];
    __syncthreads();
    int e0 = c * chunkSz, e1 = min(e0 + chunkSz, nE);
    for (int e = e0 + tid; e < e1; e += 256) {
        int s = src[e];
        int pos = atomicAdd(&cur[s >> 8], 1);       // LDS atomic
        ss[pos] = s;
    }
}

// Stage 4: one block per bucket; LDS 256-bin histogram; plain stores.
__global__ __launch_bounds__(256) void count_kernel(
    const int* __restrict__ ss, const int* __restrict__ bucket_base,
    int* __restrict__ outdeg, int N)
{
    __shared__ int hist[256];
    int b = blockIdx.x, tid = threadIdx.x;
    hist[tid] = 0;
    __syncthreads();
    int e0 = bucket_base[b], e1 = bucket_base[b + 1];
    for (int e = e0 + tid; e < e1; e += 256)
        atomicAdd(&hist[ss[e] & 255], 1);           // LDS atomic
    __syncthreads();
    int n = b * 256 + tid;
    if (n < N) outdeg[n] = hist[tid];
}

// ---------------------------------------------------------------------------
// row_ptr[n] = lower_bound(dst, n); dst is sorted.
__global__ __launch_bounds__(256) void rowptr_kernel(
    const int* __restrict__ dst, int* __restrict__ row_ptr, int nE, int N)
{
    int e = blockIdx.x * 256 + threadIdx.x;
    if (e >= nE) return;
    int d = dst[e];
    if (e == 0) {
        for (int n = 0; n <= d; ++n) row_ptr[n] = 0;
    } else {
        int p = dst[e - 1];
        for (int n = p + 1; n <= d; ++n) row_ptr[n] = e;
    }
    if (e == nE - 1) {
        for (int n = d + 1; n <= N; ++n) row_ptr[n] = nE;
    }
}

// ---------------------------------------------------------------------------
// Weight prep: W_convT[o][k] = bf16(W_conv[k][o]); W1b, W2b = bf16 copies.
__global__ __launch_bounds__(256) void wprep_kernel(
    const float* __restrict__ Wc, const float* __restrict__ W1,
    const float* __restrict__ W2, ushort* __restrict__ WcT,
    ushort* __restrict__ W1b, ushort* __restrict__ W2b)
{
    int i = blockIdx.x * 256 + threadIdx.x;
    if (i < 128 * 256) {
        int o = i >> 8, k = i & 255;
        WcT[o * 256 + k] = f2bf(Wc[k * 128 + o]);
    } else if (i < 128 * 256 + 128 * 128) {
        int j = i - 128 * 256;
        W1b[j] = f2bf(W1[j]);
    } else if (i < 128 * 256 + 128 * 128 + 256 * 128) {
        int j = i - 128 * 256 - 128 * 128;
        W2b[j] = f2bf(W2[j]);
    }
}

// ---------------------------------------------------------------------------
// GEMM1: h1u[64 rows x 128 cols per block] = bf16[x @ W_conv] (unscaled).
__global__ __launch_bounds__(256) void gemm1_kernel(
    const float* __restrict__ A, const ushort* __restrict__ B,
    ushort* __restrict__ C, int nRows)
{
    __shared__ ushort As[64 * 64];    // 8 KB
    __shared__ ushort Bs[128 * 64];   // 16 KB

    const int tid  = threadIdx.x;
    const int lane = tid & 63;
    const int w    = tid >> 6;
    const int r    = lane & 15;
    const int q    = lane >> 4;
    const int row0 = blockIdx.x * 64;

    f32x4 acc[8];
#pragma unroll
    for (int t = 0; t < 8; ++t) acc[t] = (f32x4){0.f, 0.f, 0.f, 0.f};

    for (int k0 = 0; k0 < 256; k0 += 64) {
        __syncthreads();
#pragma unroll
        for (int s = 0; s < 2; ++s) {
            int idx = s * 256 + tid;
            int row = idx >> 3, kg = idx & 7;
            int g = row0 + row;
            float4 v0 = make_float4(0.f, 0.f, 0.f, 0.f), v1 = v0;
            if (g < nRows) {
                v0 = *(const float4*)&A[(size_t)g * 256 + k0 + kg * 8];
                v1 = *(const float4*)&A[(size_t)g * 256 + k0 + kg * 8 + 4];
            }
            ushort u[8];
            u[0] = f2bf(v0.x); u[1] = f2bf(v0.y); u[2] = f2bf(v0.z); u[3] = f2bf(v0.w);
            u[4] = f2bf(v1.x); u[5] = f2bf(v1.y); u[6] = f2bf(v1.z); u[7] = f2bf(v1.w);
            *(short8*)&As[row * 64 + ((kg ^ (row & 7)) * 8)] = *(const short8*)u;
        }
#pragma unroll
        for (int s = 0; s < 4; ++s) {
            int idx = s * 256 + tid;
            int col = idx >> 3, kg = idx & 7;
            *(short8*)&Bs[col * 64 + ((kg ^ (col & 7)) * 8)] =
                *(const short8*)&B[(size_t)col * 256 + k0 + kg * 8];
        }
        __syncthreads();

#pragma unroll
        for (int ks = 0; ks < 2; ++ks) {
            short8 af = *(const short8*)&As[(w * 16 + r) * 64 + (((ks * 4 + q) ^ (r & 7)) * 8)];
#pragma unroll
            for (int t = 0; t < 8; ++t) {
                short8 bf = *(const short8*)&Bs[(t * 16 + r) * 64 + (((ks * 4 + q) ^ (r & 7)) * 8)];
                acc[t] = __builtin_amdgcn_mfma_f32_16x16x32_bf16(af, bf, acc[t], 0, 0, 0);
            }
        }
    }

#pragma unroll
    for (int t = 0; t < 8; ++t) {
        int col = t * 16 + r;
#pragma unroll
        for (int reg = 0; reg < 4; ++reg) {
            int g = row0 + w * 16 + q * 4 + reg;
            if (g < nRows)
                C[(size_t)g * 128 + col] = f2bf(acc[t][reg]);
        }
    }
}

// ---------------------------------------------------------------------------
// CSR gather, 4 edges in flight per wave; per-edge scale rsqrt(outdeg[src]).
// Fuses rsqrt(indeg) + b_conv + ReLU; bf16 out.
__global__ __launch_bounds__(256) void gather_kernel(
    const ushort* __restrict__ h1, const int* __restrict__ src,
    const int* __restrict__ rp, const int* __restrict__ outdeg,
    const float* __restrict__ b_conv, ushort* __restrict__ h2, int N)
{
    int n = (blockIdx.x * 256 + threadIdx.x) >> 6;
    int lane = threadIdx.x & 63;
    if (n >= N) return;
    const int g = lane >> 4;
    const int c = lane & 15;
    int e0 = rp[n], e1 = rp[n + 1];

    float a[8];
#pragma unroll
    for (int j = 0; j < 8; ++j) a[j] = 0.f;

    int e = e0 + g;
    for (; e + 4 < e1; e += 8) {           // 2 edges in flight per lane
        int s0 = src[e], s1 = src[e + 4];
        float sc0 = rsqrtf((float)max(outdeg[s0], 1));
        float sc1 = rsqrtf((float)max(outdeg[s1], 1));
        short8 v0 = *(const short8*)&h1[(size_t)s0 * 128 + c * 8];
        short8 v1 = *(const short8*)&h1[(size_t)s1 * 128 + c * 8];
#pragma unroll
        for (int j = 0; j < 8; ++j)
            a[j] = fmaf(sc0, bf2f((unsigned short)v0[j]),
                        fmaf(sc1, bf2f((unsigned short)v1[j]), a[j]));
    }
    if (e < e1) {
        int s0 = src[e];
        float sc0 = rsqrtf((float)max(outdeg[s0], 1));
        short8 v0 = *(const short8*)&h1[(size_t)s0 * 128 + c * 8];
#pragma unroll
        for (int j = 0; j < 8; ++j)
            a[j] = fmaf(sc0, bf2f((unsigned short)v0[j]), a[j]);
    }

#pragma unroll
    for (int j = 0; j < 8; ++j) {
        a[j] += __shfl_xor(a[j], 16, 64);
        a[j] += __shfl_xor(a[j], 32, 64);
    }

    if (g == 0) {
        float sc = rsqrtf((float)max(e1 - e0, 1));
        ushort o[8];
#pragma unroll
        for (int j = 0; j < 8; ++j)
            o[j] = f2bf(fmaxf(fmaf(a[j], sc, b_conv[c * 8 + j]), 0.f));
        *(short8*)&h2[(size_t)n * 128 + c * 8] = *(const short8*)o;
    }
}

// ---------------------------------------------------------------------------
// Fused GEMM2+GEMM3: per 64-row block,
//   stage1: T = relu(h2 @ W1^T + b1)        [64 x 128] -> bf16 in LDS (Ts)
//   stage2: out = T @ W2^T + b2             [64 x 256] -> f32 global
// LDS: stage1 As[8K]+Bs[16K]; Ts aliases [0,16K); Bs2 at [16K,48K).
__global__ __launch_bounds__(256) void gemm23_kernel(
    const ushort* __restrict__ A, const ushort* __restrict__ W1b,
    const ushort* __restrict__ W2b, const float* __restrict__ b1,
    const float* __restrict__ b2, float* __restrict__ out, int nRows)
{
    __shared__ char lds_raw[49152];
    ushort* As  = (ushort*)lds_raw;             // [64][64]   stage1
    ushort* Bs  = (ushort*)(lds_raw + 8192);    // [128][64]  stage1
    ushort* Ts  = (ushort*)lds_raw;             // [64][128]  stage2 A
    ushort* Bs2 = (ushort*)(lds_raw + 16384);   // [256][64]  stage2 B

    const int tid  = threadIdx.x;
    const int lane = tid & 63;
    const int w    = tid >> 6;
    const int r    = lane & 15;
    const int q    = lane >> 4;
    const int row0 = blockIdx.x * 64;

    // ---------------- stage 1: h2 @ W1^T ----------------
    f32x4 acc1[8];
#pragma unroll
    for (int t = 0; t < 8; ++t) acc1[t] = (f32x4){0.f, 0.f, 0.f, 0.f};

    for (int k0 = 0; k0 < 128; k0 += 64) {
        __syncthreads();
#pragma unroll
        for (int s = 0; s < 2; ++s) {
            int idx = s * 256 + tid;
            int row = idx >> 3, kg = idx & 7;
            int g = row0 + row;
            short8 v = (short8){0, 0, 0, 0, 0, 0, 0, 0};
            if (g < nRows)
                v = *(const short8*)&A[(size_t)g * 128 + k0 + kg * 8];
            *(short8*)&As[row * 64 + ((kg ^ (row & 7)) * 8)] = v;
        }
#pragma unroll
        for (int s = 0; s < 4; ++s) {
            int idx = s * 256 + tid;
            int col = idx >> 3, kg = idx & 7;
            *(short8*)&Bs[col * 64 + ((kg ^ (col & 7)) * 8)] =
                *(const short8*)&W1b[(size_t)col * 128 + k0 + kg * 8];
        }
        __syncthreads();

#pragma unroll
        for (int ks = 0; ks < 2; ++ks) {
            short8 af = *(const short8*)&As[(w * 16 + r) * 64 + (((ks * 4 + q) ^ (r & 7)) * 8)];
#pragma unroll
            for (int t = 0; t < 8; ++t) {
                short8 bf = *(const short8*)&Bs[(t * 16 + r) * 64 + (((ks * 4 + q) ^ (r & 7)) * 8)];
                acc1[t] = __builtin_amdgcn_mfma_f32_16x16x32_bf16(af, bf, acc1[t], 0, 0, 0);
            }
        }
    }

    // T = relu(acc1 + b1) -> Ts (bf16, swizzled [64][128])
    __syncthreads();
#pragma unroll
    for (int t = 0; t < 8; ++t) {
        int col = t * 16 + r;
        float bo = b1[col];
        int slot = col >> 3;
#pragma unroll
        for (int reg = 0; reg < 4; ++reg) {
            int row = w * 16 + q * 4 + reg;
            float v = fmaxf(acc1[t][reg] + bo, 0.f);
            Ts[row * 128 + ((slot ^ (row & 7)) << 3) + (col & 7)] = f2bf(v);
        }
    }

    // ---------------- stage 2: T @ W2^T ----------------
    f32x4 acc2[16];
#pragma unroll
    for (int t = 0; t < 16; ++t) acc2[t] = (f32x4){0.f, 0.f, 0.f, 0.f};

    for (int k0 = 0; k0 < 128; k0 += 64) {
        __syncthreads();
#pragma unroll
        for (int s = 0; s < 8; ++s) {
            int idx = s * 256 + tid;         // 0..2047
            int col = idx >> 3, kg = idx & 7;
            *(short8*)&Bs2[col * 64 + ((kg ^ (col & 7)) * 8)] =
                *(const short8*)&W2b[(size_t)col * 128 + k0 + kg * 8];
        }
        __syncthreads();

#pragma unroll
        for (int ks = 0; ks < 2; ++ks) {
            int slot = (k0 >> 3) + ks * 4 + q;       // 0..15 within Ts row
            short8 af = *(const short8*)&Ts[(w * 16 + r) * 128 + ((slot ^ (r & 7)) * 8)];
#pragma unroll
            for (int t = 0; t < 16; ++t) {
                short8 bf = *(const short8*)&Bs2[(t * 16 + r) * 64 + (((ks * 4 + q) ^ (r & 7)) * 8)];
                acc2[t] = __builtin_amdgcn_mfma_f32_16x16x32_bf16(af, bf, acc2[t], 0, 0, 0);
            }
        }
    }

    // epilogue: f32 out + b2
#pragma unroll
    for (int t = 0; t < 16; ++t) {
        int col = t * 16 + r;
        float bo = b2[col];
#pragma unroll
        for (int reg = 0; reg < 4; ++reg) {
            int g = row0 + w * 16 + q * 4 + reg;
            if (g < nRows)
                out[(size_t)g * 256 + col] = acc2[t][reg] + bo;
        }
    }
}

// ---------------------------------------------------------------------------
extern "C" void kernel_launch(void* const* d_in, const int* in_sizes, int n_in,
                              void* d_out, int out_size, void* d_ws, size_t ws_size,
                              hipStream_t stream)
{
    const float* x      = (const float*)d_in[0];
    const int*   src    = (const int*)d_in[1];
    const int*   dst    = (const int*)d_in[2];
    const float* W_conv = (const float*)d_in[3];
    const float* b_conv = (const float*)d_in[4];
    const float* W1     = (const float*)d_in[5];
    const float* b1     = (const float*)d_in[6];
    const float* W2     = (const float*)d_in[7];
    const float* b2     = (const float*)d_in[8];
    float* out = (float*)d_out;

    const int N  = in_sizes[0] / 256;   // 100000
    const int nE = in_sizes[1];         // 1600000

    const int nBuk    = (N + 255) >> 8;                 // 391
    const int chunkSz = (nE + NCHUNK - 1) / NCHUNK;     // 6250

    // ws layout (ushort units for bf16 region, then ints):
    // h1 [N*128] | h2 [N*128] | WcT [128*256] | W1b [128*128] | W2b [256*128]
    // | outdeg [N] | rp [N+1] | bucket_base [nBuk+1] | tot [nBuk]
    // | M [nBuk*NCHUNK] | ss [nE]
    ushort* h1  = (ushort*)d_ws;
    ushort* h2  = h1 + (size_t)N * 128;
    ushort* WcT = h2 + (size_t)N * 128;
    ushort* W1b = WcT + 128 * 256;
    ushort* W2b = W1b + 128 * 128;
    int* outdeg = (int*)(W2b + 256 * 128);
    int* rp     = outdeg + N;
    int* bb     = rp + (N + 1);
    int* tot    = bb + (nBuk + 1);
    int* M      = tot + nBuk;
    int* ss     = M + nBuk * NCHUNK;

    wprep_kernel<<<(128 * 256 + 128 * 128 + 256 * 128 + 255) / 256, 256, 0, stream>>>(
        W_conv, W1, W2, WcT, W1b, W2b);

    // ---- atomic-free out-degree (bucket sort) ----
    hist1_kernel<<<NCHUNK, 256, 0, stream>>>(src, M, nE, nBuk, chunkSz);
    scanA_kernel<<<nBuk, 256, 0, stream>>>(M, tot);
    scanB_kernel<<<1, 512, 0, stream>>>(tot, bb, nBuk);
    scatter_keys_kernel<<<NCHUNK, 256, 0, stream>>>(src, M, bb, ss, nE, nBuk, chunkSz);
    count_kernel<<<nBuk, 256, 0, stream>>>(ss, bb, outdeg, N);

    const int nBlocks = (N + 63) / 64;   // 1563
    // h1 = bf16[x @ W_conv]  (unscaled)
    gemm1_kernel<<<nBlocks, 256, 0, stream>>>(x, WcT, h1, N);

    rowptr_kernel<<<(nE + 255) / 256, 256, 0, stream>>>(dst, rp, nE, N);

    // h2 = bf16[relu( (sum_e rsqrt(outdeg[src])*h1[src]) * rsqrt(indeg) + b_conv )]
    gather_kernel<<<(N * 64 + 255) / 256, 256, 0, stream>>>(
        h1, src, rp, outdeg, b_conv, h2, N);

    // out = relu(h2 @ W1^T + b1) @ W2^T + b2   (single fused kernel)
    gemm23_kernel<<<nBlocks, 256, 0, stream>>>(h2, W1b, W2b, b1, b2, out, N);
}

// Round 8
// 185.429 us; speedup vs baseline: 1.5794x; 1.0985x over previous
//
#include <hip/hip_runtime.h>
#include <hip/hip_bf16.h>

// N=100000 nodes, E=1.6M edges (dst-sorted), IN_C=256, HID_C=128, OUT_C=256.
// f32 inputs; GEMMs run as bf16 MFMA with f32 accumulate.
// Pipeline: wprep -> [hist1, scanA, scanB, scatter_keys, count] (atomic-free
//           outdeg) -> gemm1 -> rowptr -> gather -> gemm23 (fused).

typedef __attribute__((ext_vector_type(8))) short short8;
typedef __attribute__((ext_vector_type(4))) float f32x4;

static __device__ __forceinline__ float bf2f(unsigned int u16) {
    union { unsigned int i; float f; } c; c.i = u16 << 16; return c.f;
}
static __device__ __forceinline__ ushort f2bf(float f) {
    union { float f; unsigned int i; } c; c.f = f;
    unsigned int i = c.i;
    return (ushort)((i + 0x7FFFu + ((i >> 16) & 1u)) >> 16);   // RNE
}

constexpr int NCHUNK   = 256;   // edge chunks for bucket sort
constexpr int NBUK_MAX = 512;   // LDS array bound (actual buckets = ceil(N/256))

// ---------------------------------------------------------------------------
// Bucket-sort-based out-degree (no global atomics).
// M layout: [nBuk][NCHUNK] (bucket-major, contiguous per bucket).
__global__ __launch_bounds__(256) void hist1_kernel(
    const int* __restrict__ src, int* __restrict__ M, int nE, int nBuk, int chunkSz)
{
    __shared__ int cnt[NBUK_MAX];
    int c = blockIdx.x, tid = threadIdx.x;
    for (int i = tid; i < nBuk; i += 256) cnt[i] = 0;
    __syncthreads();
    int e0 = c * chunkSz, e1 = min(e0 + chunkSz, nE);
    for (int e = e0 + tid; e < e1; e += 256)
        atomicAdd(&cnt[src[e] >> 8], 1);            // LDS atomic
    __syncthreads();
    for (int b = tid; b < nBuk; b += 256)
        M[b * NCHUNK + c] = cnt[b];
}

__global__ __launch_bounds__(256) void scanA_kernel(
    int* __restrict__ M, int* __restrict__ tot)
{
    __shared__ int buf[2][NCHUNK];
    int b = blockIdx.x, tid = threadIdx.x;
    int v = M[b * NCHUNK + tid];
    buf[0][tid] = v;
    __syncthreads();
    int pi = 0;
#pragma unroll
    for (int off = 1; off < NCHUNK; off <<= 1) {
        int t = buf[pi][tid];
        if (tid >= off) t += buf[pi][tid - off];
        buf[pi ^ 1][tid] = t;
        __syncthreads();
        pi ^= 1;
    }
    int incl = buf[pi][tid];
    M[b * NCHUNK + tid] = incl - v;                 // exclusive
    if (tid == NCHUNK - 1) tot[b] = incl;
}

__global__ __launch_bounds__(512) void scanB_kernel(
    const int* __restrict__ tot, int* __restrict__ bucket_base, int nBuk)
{
    __shared__ int t_l[NBUK_MAX], base_l[NBUK_MAX + 1];
    int tid = threadIdx.x;
    if (tid < nBuk) t_l[tid] = tot[tid];
    __syncthreads();
    if (tid == 0) {
        int base = 0;
        for (int i = 0; i < nBuk; ++i) { base_l[i] = base; base += t_l[i]; }
        base_l[nBuk] = base;
    }
    __syncthreads();
    if (tid <= nBuk) bucket_base[tid] = base_l[tid];
}

__global__ __launch_bounds__(256) void scatter_keys_kernel(
    const int* __restrict__ src, const int* __restrict__ M,
    const int* __restrict__ bucket_base, int* __restrict__ ss,
    int nE, int nBuk, int chunkSz)
{
    __shared__ int cur[NBUK_MAX];
    int c = blockIdx.x, tid = threadIdx.x;
    for (int i = tid; i < nBuk; i += 256)
        cur[i] = M[i * NCHUNK + c] + bucket_base[i];
    __syncthreads();
    int e0 = c * chunkSz, e1 = min(e0 + chunkSz, nE);
    for (int e = e0 + tid; e < e1; e += 256) {
        int s = src[e];
        int pos = atomicAdd(&cur[s >> 8], 1);       // LDS atomic
        ss[pos] = s;
    }
}

__global__ __launch_bounds__(256) void count_kernel(
    const int* __restrict__ ss, const int* __restrict__ bucket_base,
    int* __restrict__ outdeg, int N)
{
    __shared__ int hist[256];
    int b = blockIdx.x, tid = threadIdx.x;
    hist[tid] = 0;
    __syncthreads();
    int e0 = bucket_base[b], e1 = bucket_base[b + 1];
    for (int e = e0 + tid; e < e1; e += 256)
        atomicAdd(&hist[ss[e] & 255], 1);           // LDS atomic
    __syncthreads();
    int n = b * 256 + tid;
    if (n < N) outdeg[n] = hist[tid];
}

// ---------------------------------------------------------------------------
// row_ptr[n] = lower_bound(dst, n); dst is sorted.
__global__ __launch_bounds__(256) void rowptr_kernel(
    const int* __restrict__ dst, int* __restrict__ row_ptr, int nE, int N)
{
    int e = blockIdx.x * 256 + threadIdx.x;
    if (e >= nE) return;
    int d = dst[e];
    if (e == 0) {
        for (int n = 0; n <= d; ++n) row_ptr[n] = 0;
    } else {
        int p = dst[e - 1];
        for (int n = p + 1; n <= d; ++n) row_ptr[n] = e;
    }
    if (e == nE - 1) {
        for (int n = d + 1; n <= N; ++n) row_ptr[n] = nE;
    }
}

// ---------------------------------------------------------------------------
// Weight prep: W_convT[o][k] = bf16(W_conv[k][o]); W1b, W2b = bf16 copies.
__global__ __launch_bounds__(256) void wprep_kernel(
    const float* __restrict__ Wc, const float* __restrict__ W1,
    const float* __restrict__ W2, ushort* __restrict__ WcT,
    ushort* __restrict__ W1b, ushort* __restrict__ W2b)
{
    int i = blockIdx.x * 256 + threadIdx.x;
    if (i < 128 * 256) {
        int o = i >> 8, k = i & 255;
        WcT[o * 256 + k] = f2bf(Wc[k * 128 + o]);
    } else if (i < 128 * 256 + 128 * 128) {
        int j = i - 128 * 256;
        W1b[j] = f2bf(W1[j]);
    } else if (i < 128 * 256 + 128 * 128 + 256 * 128) {
        int j = i - 128 * 256 - 128 * 128;
        W2b[j] = f2bf(W2[j]);
    }
}

// ---------------------------------------------------------------------------
// GEMM1: h1 = bf16[x @ W_conv], 128 rows x 128 cols per block, 512 threads.
// Full W_convT resident in LDS (staged once); A in 4 K-chunks with depth-2
// register prefetch. Wave w: rows wm*32..+32 (wm=w>>1), cols wn*64 (wn=w&1).
__global__ __launch_bounds__(512, 4) void gemm1_kernel(
    const float* __restrict__ A, const ushort* __restrict__ B,
    ushort* __restrict__ C, int nRows)
{
    __shared__ ushort Bs[128 * 256];   // 64 KB, full W_convT, swizzled
    __shared__ ushort As[128 * 64];    // 16 KB, one K-chunk

    const int tid  = threadIdx.x;
    const int lane = tid & 63;
    const int w    = tid >> 6;
    const int wm   = w >> 1;
    const int wn   = w & 1;
    const int r    = lane & 15;
    const int q    = lane >> 4;
    const int row0 = blockIdx.x * 128;

    // ---- stage full B once: 4096 short8 slots, 8 per thread
#pragma unroll
    for (int s = 0; s < 8; ++s) {
        int idx = s * 512 + tid;
        int col = idx >> 5, kg = idx & 31;
        *(short8*)&Bs[col * 256 + ((kg ^ (col & 7)) * 8)] =
            *(const short8*)&B[(size_t)col * 256 + kg * 8];
    }

    // ---- A slot ownership: 1024 slots (128 rows x 8 kg), 2 per thread
    int arow0 = tid >> 3,          akg0 = tid & 7;
    int arow1 = (512 + tid) >> 3,  akg1 = (512 + tid) & 7;

    float4 areg[2][2][2];   // [buf][slot][half]

#define G1_ISSUE(cc, bb)                                                     \
    {                                                                        \
        int g0 = row0 + arow0, g1 = row0 + arow1;                            \
        areg[bb][0][0] = make_float4(0.f, 0.f, 0.f, 0.f);                    \
        areg[bb][0][1] = make_float4(0.f, 0.f, 0.f, 0.f);                    \
        areg[bb][1][0] = make_float4(0.f, 0.f, 0.f, 0.f);                    \
        areg[bb][1][1] = make_float4(0.f, 0.f, 0.f, 0.f);                    \
        if (g0 < nRows) {                                                    \
            const float* p = &A[(size_t)g0 * 256 + (cc) * 64 + akg0 * 8];    \
            areg[bb][0][0] = *(const float4*)p;                              \
            areg[bb][0][1] = *(const float4*)(p + 4);                        \
        }                                                                    \
        if (g1 < nRows) {                                                    \
            const float* p = &A[(size_t)g1 * 256 + (cc) * 64 + akg1 * 8];    \
            areg[bb][1][0] = *(const float4*)p;                              \
            areg[bb][1][1] = *(const float4*)(p + 4);                        \
        }                                                                    \
    }

    G1_ISSUE(0, 0)
    G1_ISSUE(1, 1)

    f32x4 acc[8];
#pragma unroll
    for (int t = 0; t < 8; ++t) acc[t] = (f32x4){0.f, 0.f, 0.f, 0.f};

#pragma unroll
    for (int c = 0; c < 4; ++c) {
        if (c > 0) __syncthreads();          // prior compute done with As
        const int buf = c & 1;
        // convert + write chunk c into As
#pragma unroll
        for (int s = 0; s < 2; ++s) {
            int arow = s ? arow1 : arow0;
            int akg  = s ? akg1  : akg0;
            float4 v0 = areg[buf][s][0], v1 = areg[buf][s][1];
            ushort u[8];
            u[0] = f2bf(v0.x); u[1] = f2bf(v0.y); u[2] = f2bf(v0.z); u[3] = f2bf(v0.w);
            u[4] = f2bf(v1.x); u[5] = f2bf(v1.y); u[6] = f2bf(v1.z); u[7] = f2bf(v1.w);
            *(short8*)&As[arow * 64 + ((akg ^ (arow & 7)) * 8)] = *(const short8*)u;
        }
        if (c + 2 < 4) G1_ISSUE(c + 2, buf)  // refill consumed buffer
        __syncthreads();
        // compute: 2 K-steps of 32
#pragma unroll
        for (int ks = 0; ks < 2; ++ks) {
            int sA = ks * 4 + q;
            int ra0 = wm * 32 + r, ra1 = wm * 32 + 16 + r;
            short8 a0 = *(const short8*)&As[ra0 * 64 + ((sA ^ (ra0 & 7)) * 8)];
            short8 a1 = *(const short8*)&As[ra1 * 64 + ((sA ^ (ra1 & 7)) * 8)];
            int sB = c * 8 + ks * 4 + q;
#pragma unroll
            for (int t = 0; t < 4; ++t) {
                int col = wn * 64 + t * 16 + r;
                short8 b = *(const short8*)&Bs[col * 256 + ((sB ^ (col & 7)) * 8)];
                acc[t]     = __builtin_amdgcn_mfma_f32_16x16x32_bf16(a0, b, acc[t], 0, 0, 0);
                acc[4 + t] = __builtin_amdgcn_mfma_f32_16x16x32_bf16(a1, b, acc[4 + t], 0, 0, 0);
            }
        }
    }
#undef G1_ISSUE

    // epilogue: bf16 h1
#pragma unroll
    for (int fr = 0; fr < 2; ++fr)
#pragma unroll
        for (int t = 0; t < 4; ++t) {
            int col = wn * 64 + t * 16 + r;
#pragma unroll
            for (int reg = 0; reg < 4; ++reg) {
                int g = row0 + wm * 32 + fr * 16 + q * 4 + reg;
                if (g < nRows)
                    C[(size_t)g * 128 + col] = f2bf(acc[fr * 4 + t][reg]);
            }
        }
}

// ---------------------------------------------------------------------------
// CSR gather, 4 edges in flight per wave; per-edge scale rsqrt(outdeg[src]).
// Fuses rsqrt(indeg) + b_conv + ReLU; bf16 out.
__global__ __launch_bounds__(256) void gather_kernel(
    const ushort* __restrict__ h1, const int* __restrict__ src,
    const int* __restrict__ rp, const int* __restrict__ outdeg,
    const float* __restrict__ b_conv, ushort* __restrict__ h2, int N)
{
    int n = (blockIdx.x * 256 + threadIdx.x) >> 6;
    int lane = threadIdx.x & 63;
    if (n >= N) return;
    const int g = lane >> 4;
    const int c = lane & 15;
    int e0 = rp[n], e1 = rp[n + 1];

    float a[8];
#pragma unroll
    for (int j = 0; j < 8; ++j) a[j] = 0.f;

    int e = e0 + g;
    for (; e + 4 < e1; e += 8) {           // 2 edges in flight per lane
        int s0 = src[e], s1 = src[e + 4];
        float sc0 = rsqrtf((float)max(outdeg[s0], 1));
        float sc1 = rsqrtf((float)max(outdeg[s1], 1));
        short8 v0 = *(const short8*)&h1[(size_t)s0 * 128 + c * 8];
        short8 v1 = *(const short8*)&h1[(size_t)s1 * 128 + c * 8];
#pragma unroll
        for (int j = 0; j < 8; ++j)
            a[j] = fmaf(sc0, bf2f((unsigned short)v0[j]),
                        fmaf(sc1, bf2f((unsigned short)v1[j]), a[j]));
    }
    if (e < e1) {
        int s0 = src[e];
        float sc0 = rsqrtf((float)max(outdeg[s0], 1));
        short8 v0 = *(const short8*)&h1[(size_t)s0 * 128 + c * 8];
#pragma unroll
        for (int j = 0; j < 8; ++j)
            a[j] = fmaf(sc0, bf2f((unsigned short)v0[j]), a[j]);
    }

#pragma unroll
    for (int j = 0; j < 8; ++j) {
        a[j] += __shfl_xor(a[j], 16, 64);
        a[j] += __shfl_xor(a[j], 32, 64);
    }

    if (g == 0) {
        float sc = rsqrtf((float)max(e1 - e0, 1));
        ushort o[8];
#pragma unroll
        for (int j = 0; j < 8; ++j)
            o[j] = f2bf(fmaxf(fmaf(a[j], sc, b_conv[c * 8 + j]), 0.f));
        *(short8*)&h2[(size_t)n * 128 + c * 8] = *(const short8*)o;
    }
}

// ---------------------------------------------------------------------------
// Fused GEMM2+GEMM3: 128 rows per block, 512 threads, weights fully LDS-
// resident (staged once). stage1: T = relu(h2@W1^T+b1) -> bf16 into As's
// space; stage2: out = T@W2^T+b2 -> f32. 3 barriers total, no K-loop barriers.
__global__ __launch_bounds__(512, 2) void gemm23_kernel(
    const ushort* __restrict__ A, const ushort* __restrict__ W1b,
    const ushort* __restrict__ W2b, const float* __restrict__ b1,
    const float* __restrict__ b2, float* __restrict__ out, int nRows)
{
    __shared__ ushort AsTs[128 * 128];  // 32 KB: h2 tile, then T tile
    __shared__ ushort W1s[128 * 128];   // 32 KB
    __shared__ ushort W2s[256 * 128];   // 64 KB

    const int tid  = threadIdx.x;
    const int lane = tid & 63;
    const int w    = tid >> 6;
    const int wm   = w >> 1;
    const int wn   = w & 1;
    const int r    = lane & 15;
    const int q    = lane >> 4;
    const int row0 = blockIdx.x * 128;

    // ---- stage As (guarded) + W1 + W2, all swizzled
#pragma unroll
    for (int s = 0; s < 4; ++s) {
        int idx = s * 512 + tid;
        int row = idx >> 4, kg = idx & 15;
        int g = row0 + row;
        short8 v = (short8){0, 0, 0, 0, 0, 0, 0, 0};
        if (g < nRows) v = *(const short8*)&A[(size_t)g * 128 + kg * 8];
        *(short8*)&AsTs[row * 128 + ((kg ^ (row & 7)) * 8)] = v;
    }
#pragma unroll
    for (int s = 0; s < 4; ++s) {
        int idx = s * 512 + tid;
        int col = idx >> 4, kg = idx & 15;
        *(short8*)&W1s[col * 128 + ((kg ^ (col & 7)) * 8)] =
            *(const short8*)&W1b[(size_t)col * 128 + kg * 8];
    }
#pragma unroll
    for (int s = 0; s < 8; ++s) {
        int idx = s * 512 + tid;
        int col = idx >> 4, kg = idx & 15;
        *(short8*)&W2s[col * 128 + ((kg ^ (col & 7)) * 8)] =
            *(const short8*)&W2b[(size_t)col * 128 + kg * 8];
    }
    __syncthreads();

    // ---- stage1: T = h2 @ W1^T  (K=128, no inner barriers)
    f32x4 acc1[8];
#pragma unroll
    for (int t = 0; t < 8; ++t) acc1[t] = (f32x4){0.f, 0.f, 0.f, 0.f};
#pragma unroll
    for (int ks = 0; ks < 4; ++ks) {
        int sA = ks * 4 + q;
        int ra0 = wm * 32 + r, ra1 = wm * 32 + 16 + r;
        short8 a0 = *(const short8*)&AsTs[ra0 * 128 + ((sA ^ (ra0 & 7)) * 8)];
        short8 a1 = *(const short8*)&AsTs[ra1 * 128 + ((sA ^ (ra1 & 7)) * 8)];
#pragma unroll
        for (int t = 0; t < 4; ++t) {
            int col = wn * 64 + t * 16 + r;
            short8 b = *(const short8*)&W1s[col * 128 + ((sA ^ (col & 7)) * 8)];
            acc1[t]     = __builtin_amdgcn_mfma_f32_16x16x32_bf16(a0, b, acc1[t], 0, 0, 0);
            acc1[4 + t] = __builtin_amdgcn_mfma_f32_16x16x32_bf16(a1, b, acc1[4 + t], 0, 0, 0);
        }
    }
    __syncthreads();   // all As reads done -> safe to overwrite with T

    // ---- T = relu(acc1 + b1) -> AsTs (bf16, swizzled)
#pragma unroll
    for (int fr = 0; fr < 2; ++fr)
#pragma unroll
        for (int t = 0; t < 4; ++t) {
            int col = wn * 64 + t * 16 + r;
            float bo = b1[col];
#pragma unroll
            for (int reg = 0; reg < 4; ++reg) {
                int row = wm * 32 + fr * 16 + q * 4 + reg;
                float v = fmaxf(acc1[fr * 4 + t][reg] + bo, 0.f);
                AsTs[row * 128 + (((col >> 3) ^ (row & 7)) * 8) + (col & 7)] = f2bf(v);
            }
        }
    __syncthreads();

    // ---- stage2: out = T @ W2^T  (K=128, no inner barriers)
    f32x4 acc2[16];
#pragma unroll
    for (int t = 0; t < 16; ++t) acc2[t] = (f32x4){0.f, 0.f, 0.f, 0.f};
#pragma unroll
    for (int ks = 0; ks < 4; ++ks) {
        int sA = ks * 4 + q;
        int ra0 = wm * 32 + r, ra1 = wm * 32 + 16 + r;
        short8 a0 = *(const short8*)&AsTs[ra0 * 128 + ((sA ^ (ra0 & 7)) * 8)];
        short8 a1 = *(const short8*)&AsTs[ra1 * 128 + ((sA ^ (ra1 & 7)) * 8)];
#pragma unroll
        for (int t = 0; t < 8; ++t) {
            int col = wn * 128 + t * 16 + r;
            short8 b = *(const short8*)&W2s[col * 128 + ((sA ^ (col & 7)) * 8)];
            acc2[t]     = __builtin_amdgcn_mfma_f32_16x16x32_bf16(a0, b, acc2[t], 0, 0, 0);
            acc2[8 + t] = __builtin_amdgcn_mfma_f32_16x16x32_bf16(a1, b, acc2[8 + t], 0, 0, 0);
        }
    }

    // ---- epilogue: f32 out + b2
#pragma unroll
    for (int fr = 0; fr < 2; ++fr)
#pragma unroll
        for (int t = 0; t < 8; ++t) {
            int col = wn * 128 + t * 16 + r;
            float bo = b2[col];
#pragma unroll
            for (int reg = 0; reg < 4; ++reg) {
                int g = row0 + wm * 32 + fr * 16 + q * 4 + reg;
                if (g < nRows)
                    out[(size_t)g * 256 + col] = acc2[fr * 8 + t][reg] + bo;
            }
        }
}

// ---------------------------------------------------------------------------
extern "C" void kernel_launch(void* const* d_in, const int* in_sizes, int n_in,
                              void* d_out, int out_size, void* d_ws, size_t ws_size,
                              hipStream_t stream)
{
    const float* x      = (const float*)d_in[0];
    const int*   src    = (const int*)d_in[1];
    const int*   dst    = (const int*)d_in[2];
    const float* W_conv = (const float*)d_in[3];
    const float* b_conv = (const float*)d_in[4];
    const float* W1     = (const float*)d_in[5];
    const float* b1     = (const float*)d_in[6];
    const float* W2     = (const float*)d_in[7];
    const float* b2     = (const float*)d_in[8];
    float* out = (float*)d_out;

    const int N  = in_sizes[0] / 256;   // 100000
    const int nE = in_sizes[1];         // 1600000

    const int nBuk    = (N + 255) >> 8;                 // 391
    const int chunkSz = (nE + NCHUNK - 1) / NCHUNK;     // 6250

    // ws layout (ushort units for bf16 region, then ints):
    // h1 [N*128] | h2 [N*128] | WcT [128*256] | W1b [128*128] | W2b [256*128]
    // | outdeg [N] | rp [N+1] | bucket_base [nBuk+1] | tot [nBuk]
    // | M [nBuk*NCHUNK] | ss [nE]
    ushort* h1  = (ushort*)d_ws;
    ushort* h2  = h1 + (size_t)N * 128;
    ushort* WcT = h2 + (size_t)N * 128;
    ushort* W1b = WcT + 128 * 256;
    ushort* W2b = W1b + 128 * 128;
    int* outdeg = (int*)(W2b + 256 * 128);
    int* rp     = outdeg + N;
    int* bb     = rp + (N + 1);
    int* tot    = bb + (nBuk + 1);
    int* M      = tot + nBuk;
    int* ss     = M + nBuk * NCHUNK;

    wprep_kernel<<<(128 * 256 + 128 * 128 + 256 * 128 + 255) / 256, 256, 0, stream>>>(
        W_conv, W1, W2, WcT, W1b, W2b);

    // ---- atomic-free out-degree (bucket sort) ----
    hist1_kernel<<<NCHUNK, 256, 0, stream>>>(src, M, nE, nBuk, chunkSz);
    scanA_kernel<<<nBuk, 256, 0, stream>>>(M, tot);
    scanB_kernel<<<1, 512, 0, stream>>>(tot, bb, nBuk);
    scatter_keys_kernel<<<NCHUNK, 256, 0, stream>>>(src, M, bb, ss, nE, nBuk, chunkSz);
    count_kernel<<<nBuk, 256, 0, stream>>>(ss, bb, outdeg, N);

    const int nBlocks128 = (N + 127) / 128;   // 782
    // h1 = bf16[x @ W_conv]  (unscaled)
    gemm1_kernel<<<nBlocks128, 512, 0, stream>>>(x, WcT, h1, N);

    rowptr_kernel<<<(nE + 255) / 256, 256, 0, stream>>>(dst, rp, nE, N);

    // h2 = bf16[relu( (sum_e rsqrt(outdeg[src])*h1[src]) * rsqrt(indeg) + b_conv )]
    gather_kernel<<<(N * 64 + 255) / 256, 256, 0, stream>>>(
        h1, src, rp, outdeg, b_conv, h2, N);

    // out = relu(h2 @ W1^T + b1) @ W2^T + b2   (single fused kernel)
    gemm23_kernel<<<nBlocks128, 512, 0, stream>>>(h2, W1b, W2b, b1, b2, out, N);
}

// Round 9
// 184.788 us; speedup vs baseline: 1.5849x; 1.0035x over previous
//
#include <hip/hip_runtime.h>
#include <hip/hip_bf16.h>

// N=100000 nodes, E=1.6M edges (dst-sorted), IN_C=256, HID_C=128, OUT_C=256.
// f32 inputs; GEMMs run as bf16 MFMA with f32 accumulate.
// Pipeline: prep(wprep+hist1+rowptr fused) -> scanA -> scanB -> scatter_keys
//           -> count -> gemm1(scale fused in epilogue) -> gather -> gemm23.

typedef __attribute__((ext_vector_type(8))) short short8;
typedef __attribute__((ext_vector_type(4))) float f32x4;

static __device__ __forceinline__ float bf2f(unsigned int u16) {
    union { unsigned int i; float f; } c; c.i = u16 << 16; return c.f;
}
static __device__ __forceinline__ ushort f2bf(float f) {
    union { float f; unsigned int i; } c; c.f = f;
    unsigned int i = c.i;
    return (ushort)((i + 0x7FFFu + ((i >> 16) & 1u)) >> 16);   // RNE
}

constexpr int NCHUNK   = 256;   // edge chunks for bucket sort
constexpr int NBUK_MAX = 512;   // LDS bound (actual buckets = ceil(N/256))
constexpr int WPREP_BLOCKS = (128 * 256 + 128 * 128 + 256 * 128) / 256;  // 320

// ---------------------------------------------------------------------------
// prep: fused wprep + hist1 + rowptr (all independent).
// blocks [0,320): weight convert; [320,320+NCHUNK): per-chunk bucket hist;
// rest: rowptr boundary fill.
__global__ __launch_bounds__(256) void prep_kernel(
    const float* __restrict__ Wc, const float* __restrict__ W1,
    const float* __restrict__ W2, ushort* __restrict__ WcT,
    ushort* __restrict__ W1b, ushort* __restrict__ W2b,
    const int* __restrict__ src, int* __restrict__ M,
    const int* __restrict__ dst, int* __restrict__ row_ptr,
    int nE, int N, int nBuk, int chunkSz)
{
    __shared__ int cnt[NBUK_MAX];
    const int bid = blockIdx.x, tid = threadIdx.x;

    if (bid < WPREP_BLOCKS) {
        int i = bid * 256 + tid;
        if (i < 128 * 256) {
            int o = i >> 8, k = i & 255;
            WcT[o * 256 + k] = f2bf(Wc[k * 128 + o]);
        } else if (i < 128 * 256 + 128 * 128) {
            int j = i - 128 * 256;
            W1b[j] = f2bf(W1[j]);
        } else {
            int j = i - 128 * 256 - 128 * 128;
            W2b[j] = f2bf(W2[j]);
        }
        return;
    }
    if (bid < WPREP_BLOCKS + NCHUNK) {
        int c = bid - WPREP_BLOCKS;
        for (int i = tid; i < nBuk; i += 256) cnt[i] = 0;
        __syncthreads();
        int e0 = c * chunkSz, e1 = min(e0 + chunkSz, nE);
        for (int e = e0 + tid; e < e1; e += 256)
            atomicAdd(&cnt[src[e] >> 8], 1);        // LDS atomic
        __syncthreads();
        for (int b = tid; b < nBuk; b += 256)
            M[b * NCHUNK + c] = cnt[b];
        return;
    }
    // rowptr
    int e = (bid - WPREP_BLOCKS - NCHUNK) * 256 + tid;
    if (e >= nE) return;
    int d = dst[e];
    if (e == 0) {
        for (int n = 0; n <= d; ++n) row_ptr[n] = 0;
    } else {
        int p = dst[e - 1];
        for (int n = p + 1; n <= d; ++n) row_ptr[n] = e;
    }
    if (e == nE - 1) {
        for (int n = d + 1; n <= N; ++n) row_ptr[n] = nE;
    }
}

// ---------------------------------------------------------------------------
__global__ __launch_bounds__(256) void scanA_kernel(
    int* __restrict__ M, int* __restrict__ tot)
{
    __shared__ int buf[2][NCHUNK];
    int b = blockIdx.x, tid = threadIdx.x;
    int v = M[b * NCHUNK + tid];
    buf[0][tid] = v;
    __syncthreads();
    int pi = 0;
#pragma unroll
    for (int off = 1; off < NCHUNK; off <<= 1) {
        int t = buf[pi][tid];
        if (tid >= off) t += buf[pi][tid - off];
        buf[pi ^ 1][tid] = t;
        __syncthreads();
        pi ^= 1;
    }
    int incl = buf[pi][tid];
    M[b * NCHUNK + tid] = incl - v;                 // exclusive
    if (tid == NCHUNK - 1) tot[b] = incl;
}

__global__ __launch_bounds__(512) void scanB_kernel(
    const int* __restrict__ tot, int* __restrict__ bucket_base, int nBuk)
{
    __shared__ int t_l[NBUK_MAX], base_l[NBUK_MAX + 1];
    int tid = threadIdx.x;
    if (tid < nBuk) t_l[tid] = tot[tid];
    __syncthreads();
    if (tid == 0) {
        int base = 0;
        for (int i = 0; i < nBuk; ++i) { base_l[i] = base; base += t_l[i]; }
        base_l[nBuk] = base;
    }
    __syncthreads();
    if (tid <= nBuk) bucket_base[tid] = base_l[tid];
}

__global__ __launch_bounds__(256) void scatter_keys_kernel(
    const int* __restrict__ src, const int* __restrict__ M,
    const int* __restrict__ bucket_base, int* __restrict__ ss,
    int nE, int nBuk, int chunkSz)
{
    __shared__ int cur[NBUK_MAX];
    int c = blockIdx.x, tid = threadIdx.x;
    for (int i = tid; i < nBuk; i += 256)
        cur[i] = M[i * NCHUNK + c] + bucket_base[i];
    __syncthreads();
    int e0 = c * chunkSz, e1 = min(e0 + chunkSz, nE);
    for (int e = e0 + tid; e < e1; e += 256) {
        int s = src[e];
        int pos = atomicAdd(&cur[s >> 8], 1);       // LDS atomic
        ss[pos] = s;
    }
}

__global__ __launch_bounds__(256) void count_kernel(
    const int* __restrict__ ss, const int* __restrict__ bucket_base,
    int* __restrict__ outdeg, int N)
{
    __shared__ int hist[256];
    int b = blockIdx.x, tid = threadIdx.x;
    hist[tid] = 0;
    __syncthreads();
    int e0 = bucket_base[b], e1 = bucket_base[b + 1];
    for (int e = e0 + tid; e < e1; e += 256)
        atomicAdd(&hist[ss[e] & 255], 1);           // LDS atomic
    __syncthreads();
    int n = b * 256 + tid;
    if (n < N) outdeg[n] = hist[tid];
}

// ---------------------------------------------------------------------------
// GEMM1: h1 = bf16[rsqrt(outdeg) * (x @ W_conv)], 128x128 per block, 512 thr.
// Full W_convT resident in LDS (staged once); A in 4 K-chunks with depth-2
// register prefetch; src-side normalization fused in the epilogue.
__global__ __launch_bounds__(512, 4) void gemm1_kernel(
    const float* __restrict__ A, const ushort* __restrict__ B,
    const int* __restrict__ outdeg, ushort* __restrict__ C, int nRows)
{
    __shared__ ushort Bs[128 * 256];   // 64 KB, full W_convT, swizzled
    __shared__ ushort As[128 * 64];    // 16 KB, one K-chunk
    __shared__ float rowscale[128];

    const int tid  = threadIdx.x;
    const int lane = tid & 63;
    const int w    = tid >> 6;
    const int wm   = w >> 1;
    const int wn   = w & 1;
    const int r    = lane & 15;
    const int q    = lane >> 4;
    const int row0 = blockIdx.x * 128;

    if (tid < 128) {
        int g = row0 + tid;
        int dv = (g < nRows) ? outdeg[g] : 1;
        rowscale[tid] = rsqrtf((float)max(dv, 1));
    }

    // ---- stage full B once: 4096 short8 slots, 8 per thread
#pragma unroll
    for (int s = 0; s < 8; ++s) {
        int idx = s * 512 + tid;
        int col = idx >> 5, kg = idx & 31;
        *(short8*)&Bs[col * 256 + ((kg ^ (col & 7)) * 8)] =
            *(const short8*)&B[(size_t)col * 256 + kg * 8];
    }

    // ---- A slot ownership: 1024 slots (128 rows x 8 kg), 2 per thread
    int arow0 = tid >> 3,          akg0 = tid & 7;
    int arow1 = (512 + tid) >> 3,  akg1 = (512 + tid) & 7;

    float4 areg[2][2][2];   // [buf][slot][half]

#define G1_ISSUE(cc, bb)                                                     \
    {                                                                        \
        int g0 = row0 + arow0, g1 = row0 + arow1;                            \
        areg[bb][0][0] = make_float4(0.f, 0.f, 0.f, 0.f);                    \
        areg[bb][0][1] = make_float4(0.f, 0.f, 0.f, 0.f);                    \
        areg[bb][1][0] = make_float4(0.f, 0.f, 0.f, 0.f);                    \
        areg[bb][1][1] = make_float4(0.f, 0.f, 0.f, 0.f);                    \
        if (g0 < nRows) {                                                    \
            const float* p = &A[(size_t)g0 * 256 + (cc) * 64 + akg0 * 8];    \
            areg[bb][0][0] = *(const float4*)p;                              \
            areg[bb][0][1] = *(const float4*)(p + 4);                        \
        }                                                                    \
        if (g1 < nRows) {                                                    \
            const float* p = &A[(size_t)g1 * 256 + (cc) * 64 + akg1 * 8];    \
            areg[bb][1][0] = *(const float4*)p;                              \
            areg[bb][1][1] = *(const float4*)(p + 4);                        \
        }                                                                    \
    }

    G1_ISSUE(0, 0)
    G1_ISSUE(1, 1)

    f32x4 acc[8];
#pragma unroll
    for (int t = 0; t < 8; ++t) acc[t] = (f32x4){0.f, 0.f, 0.f, 0.f};

#pragma unroll
    for (int c = 0; c < 4; ++c) {
        if (c > 0) __syncthreads();          // prior compute done with As
        const int buf = c & 1;
#pragma unroll
        for (int s = 0; s < 2; ++s) {
            int arow = s ? arow1 : arow0;
            int akg  = s ? akg1  : akg0;
            float4 v0 = areg[buf][s][0], v1 = areg[buf][s][1];
            ushort u[8];
            u[0] = f2bf(v0.x); u[1] = f2bf(v0.y); u[2] = f2bf(v0.z); u[3] = f2bf(v0.w);
            u[4] = f2bf(v1.x); u[5] = f2bf(v1.y); u[6] = f2bf(v1.z); u[7] = f2bf(v1.w);
            *(short8*)&As[arow * 64 + ((akg ^ (arow & 7)) * 8)] = *(const short8*)u;
        }
        if (c + 2 < 4) G1_ISSUE(c + 2, buf)  // refill consumed buffer
        __syncthreads();
#pragma unroll
        for (int ks = 0; ks < 2; ++ks) {
            int sA = ks * 4 + q;
            int ra0 = wm * 32 + r, ra1 = wm * 32 + 16 + r;
            short8 a0 = *(const short8*)&As[ra0 * 64 + ((sA ^ (ra0 & 7)) * 8)];
            short8 a1 = *(const short8*)&As[ra1 * 64 + ((sA ^ (ra1 & 7)) * 8)];
            int sB = c * 8 + ks * 4 + q;
#pragma unroll
            for (int t = 0; t < 4; ++t) {
                int col = wn * 64 + t * 16 + r;
                short8 b = *(const short8*)&Bs[col * 256 + ((sB ^ (col & 7)) * 8)];
                acc[t]     = __builtin_amdgcn_mfma_f32_16x16x32_bf16(a0, b, acc[t], 0, 0, 0);
                acc[4 + t] = __builtin_amdgcn_mfma_f32_16x16x32_bf16(a1, b, acc[4 + t], 0, 0, 0);
            }
        }
    }
#undef G1_ISSUE

    // epilogue: apply src-side normalization, store bf16 h1
#pragma unroll
    for (int fr = 0; fr < 2; ++fr)
#pragma unroll
        for (int t = 0; t < 4; ++t) {
            int col = wn * 64 + t * 16 + r;
#pragma unroll
            for (int reg = 0; reg < 4; ++reg) {
                int lr = wm * 32 + fr * 16 + q * 4 + reg;
                int g = row0 + lr;
                if (g < nRows)
                    C[(size_t)g * 128 + col] = f2bf(acc[fr * 4 + t][reg] * rowscale[lr]);
            }
        }
}

// ---------------------------------------------------------------------------
// CSR gather over pre-scaled h1: pure sum, 4 edges in flight per lane
// (16 per node). Fuses rsqrt(indeg) + b_conv + ReLU; bf16 out.
__global__ __launch_bounds__(256) void gather_kernel(
    const ushort* __restrict__ h1, const int* __restrict__ src,
    const int* __restrict__ rp, const float* __restrict__ b_conv,
    ushort* __restrict__ h2, int N)
{
    int n = (blockIdx.x * 256 + threadIdx.x) >> 6;
    int lane = threadIdx.x & 63;
    if (n >= N) return;
    const int g = lane >> 4;
    const int c = lane & 15;
    int e0 = rp[n], e1 = rp[n + 1];

    float a[8];
#pragma unroll
    for (int j = 0; j < 8; ++j) a[j] = 0.f;

    int e = e0 + g;
    for (; e + 12 < e1; e += 16) {         // 4 edges in flight per lane
        int s0 = src[e], s1 = src[e + 4], s2 = src[e + 8], s3 = src[e + 12];
        short8 v0 = *(const short8*)&h1[((size_t)(unsigned)s0 << 7) + c * 8];
        short8 v1 = *(const short8*)&h1[((size_t)(unsigned)s1 << 7) + c * 8];
        short8 v2 = *(const short8*)&h1[((size_t)(unsigned)s2 << 7) + c * 8];
        short8 v3 = *(const short8*)&h1[((size_t)(unsigned)s3 << 7) + c * 8];
#pragma unroll
        for (int j = 0; j < 8; ++j)
            a[j] += (bf2f((unsigned short)v0[j]) + bf2f((unsigned short)v1[j]))
                  + (bf2f((unsigned short)v2[j]) + bf2f((unsigned short)v3[j]));
    }
    for (; e < e1; e += 4) {
        short8 v0 = *(const short8*)&h1[((size_t)(unsigned)src[e] << 7) + c * 8];
#pragma unroll
        for (int j = 0; j < 8; ++j)
            a[j] += bf2f((unsigned short)v0[j]);
    }

#pragma unroll
    for (int j = 0; j < 8; ++j) {
        a[j] += __shfl_xor(a[j], 16, 64);
        a[j] += __shfl_xor(a[j], 32, 64);
    }

    if (g == 0) {
        float sc = rsqrtf((float)max(e1 - e0, 1));
        ushort o[8];
#pragma unroll
        for (int j = 0; j < 8; ++j)
            o[j] = f2bf(fmaxf(fmaf(a[j], sc, b_conv[c * 8 + j]), 0.f));
        *(short8*)&h2[((size_t)(unsigned)n << 7) + c * 8] = *(const short8*)o;
    }
}

// ---------------------------------------------------------------------------
// Fused GEMM2+GEMM3: 128 rows per block, 512 threads, weights fully LDS-
// resident (staged once). stage1: T = relu(h2@W1^T+b1) -> bf16 into As's
// space; stage2: out = T@W2^T+b2 -> f32. 3 barriers total.
__global__ __launch_bounds__(512, 2) void gemm23_kernel(
    const ushort* __restrict__ A, const ushort* __restrict__ W1b,
    const ushort* __restrict__ W2b, const float* __restrict__ b1,
    const float* __restrict__ b2, float* __restrict__ out, int nRows)
{
    __shared__ ushort AsTs[128 * 128];  // 32 KB: h2 tile, then T tile
    __shared__ ushort W1s[128 * 128];   // 32 KB
    __shared__ ushort W2s[256 * 128];   // 64 KB

    const int tid  = threadIdx.x;
    const int lane = tid & 63;
    const int w    = tid >> 6;
    const int wm   = w >> 1;
    const int wn   = w & 1;
    const int r    = lane & 15;
    const int q    = lane >> 4;
    const int row0 = blockIdx.x * 128;

    // ---- stage As (guarded) + W1 + W2, all swizzled
#pragma unroll
    for (int s = 0; s < 4; ++s) {
        int idx = s * 512 + tid;
        int row = idx >> 4, kg = idx & 15;
        int g = row0 + row;
        short8 v = (short8){0, 0, 0, 0, 0, 0, 0, 0};
        if (g < nRows) v = *(const short8*)&A[(size_t)g * 128 + kg * 8];
        *(short8*)&AsTs[row * 128 + ((kg ^ (row & 7)) * 8)] = v;
    }
#pragma unroll
    for (int s = 0; s < 4; ++s) {
        int idx = s * 512 + tid;
        int col = idx >> 4, kg = idx & 15;
        *(short8*)&W1s[col * 128 + ((kg ^ (col & 7)) * 8)] =
            *(const short8*)&W1b[(size_t)col * 128 + kg * 8];
    }
#pragma unroll
    for (int s = 0; s < 8; ++s) {
        int idx = s * 512 + tid;
        int col = idx >> 4, kg = idx & 15;
        *(short8*)&W2s[col * 128 + ((kg ^ (col & 7)) * 8)] =
            *(const short8*)&W2b[(size_t)col * 128 + kg * 8];
    }
    __syncthreads();

    // ---- stage1: T = h2 @ W1^T  (K=128, no inner barriers)
    f32x4 acc1[8];
#pragma unroll
    for (int t = 0; t < 8; ++t) acc1[t] = (f32x4){0.f, 0.f, 0.f, 0.f};
#pragma unroll
    for (int ks = 0; ks < 4; ++ks) {
        int sA = ks * 4 + q;
        int ra0 = wm * 32 + r, ra1 = wm * 32 + 16 + r;
        short8 a0 = *(const short8*)&AsTs[ra0 * 128 + ((sA ^ (ra0 & 7)) * 8)];
        short8 a1 = *(const short8*)&AsTs[ra1 * 128 + ((sA ^ (ra1 & 7)) * 8)];
#pragma unroll
        for (int t = 0; t < 4; ++t) {
            int col = wn * 64 + t * 16 + r;
            short8 b = *(const short8*)&W1s[col * 128 + ((sA ^ (col & 7)) * 8)];
            acc1[t]     = __builtin_amdgcn_mfma_f32_16x16x32_bf16(a0, b, acc1[t], 0, 0, 0);
            acc1[4 + t] = __builtin_amdgcn_mfma_f32_16x16x32_bf16(a1, b, acc1[4 + t], 0, 0, 0);
        }
    }
    __syncthreads();   // all As reads done -> safe to overwrite with T

    // ---- T = relu(acc1 + b1) -> AsTs (bf16, swizzled)
#pragma unroll
    for (int fr = 0; fr < 2; ++fr)
#pragma unroll
        for (int t = 0; t < 4; ++t) {
            int col = wn * 64 + t * 16 + r;
            float bo = b1[col];
#pragma unroll
            for (int reg = 0; reg < 4; ++reg) {
                int row = wm * 32 + fr * 16 + q * 4 + reg;
                float v = fmaxf(acc1[fr * 4 + t][reg] + bo, 0.f);
                AsTs[row * 128 + (((col >> 3) ^ (row & 7)) * 8) + (col & 7)] = f2bf(v);
            }
        }
    __syncthreads();

    // ---- stage2: out = T @ W2^T  (K=128, no inner barriers)
    f32x4 acc2[16];
#pragma unroll
    for (int t = 0; t < 16; ++t) acc2[t] = (f32x4){0.f, 0.f, 0.f, 0.f};
#pragma unroll
    for (int ks = 0; ks < 4; ++ks) {
        int sA = ks * 4 + q;
        int ra0 = wm * 32 + r, ra1 = wm * 32 + 16 + r;
        short8 a0 = *(const short8*)&AsTs[ra0 * 128 + ((sA ^ (ra0 & 7)) * 8)];
        short8 a1 = *(const short8*)&AsTs[ra1 * 128 + ((sA ^ (ra1 & 7)) * 8)];
#pragma unroll
        for (int t = 0; t < 8; ++t) {
            int col = wn * 128 + t * 16 + r;
            short8 b = *(const short8*)&W2s[col * 128 + ((sA ^ (col & 7)) * 8)];
            acc2[t]     = __builtin_amdgcn_mfma_f32_16x16x32_bf16(a0, b, acc2[t], 0, 0, 0);
            acc2[8 + t] = __builtin_amdgcn_mfma_f32_16x16x32_bf16(a1, b, acc2[8 + t], 0, 0, 0);
        }
    }

    // ---- epilogue: f32 out + b2
#pragma unroll
    for (int fr = 0; fr < 2; ++fr)
#pragma unroll
        for (int t = 0; t < 8; ++t) {
            int col = wn * 128 + t * 16 + r;
            float bo = b2[col];
#pragma unroll
            for (int reg = 0; reg < 4; ++reg) {
                int g = row0 + wm * 32 + fr * 16 + q * 4 + reg;
                if (g < nRows)
                    out[(size_t)g * 256 + col] = acc2[fr * 8 + t][reg] + bo;
            }
        }
}

// ---------------------------------------------------------------------------
extern "C" void kernel_launch(void* const* d_in, const int* in_sizes, int n_in,
                              void* d_out, int out_size, void* d_ws, size_t ws_size,
                              hipStream_t stream)
{
    const float* x      = (const float*)d_in[0];
    const int*   src    = (const int*)d_in[1];
    const int*   dst    = (const int*)d_in[2];
    const float* W_conv = (const float*)d_in[3];
    const float* b_conv = (const float*)d_in[4];
    const float* W1     = (const float*)d_in[5];
    const float* b1     = (const float*)d_in[6];
    const float* W2     = (const float*)d_in[7];
    const float* b2     = (const float*)d_in[8];
    float* out = (float*)d_out;

    const int N  = in_sizes[0] / 256;   // 100000
    const int nE = in_sizes[1];         // 1600000

    const int nBuk    = (N + 255) >> 8;                 // 391
    const int chunkSz = (nE + NCHUNK - 1) / NCHUNK;     // 6250

    // ws layout (ushort units for bf16 region, then ints):
    // h1 [N*128] | h2 [N*128] | WcT [128*256] | W1b [128*128] | W2b [256*128]
    // | outdeg [N] | rp [N+1] | bucket_base [nBuk+1] | tot [nBuk]
    // | M [nBuk*NCHUNK] | ss [nE]
    ushort* h1  = (ushort*)d_ws;
    ushort* h2  = h1 + (size_t)N * 128;
    ushort* WcT = h2 + (size_t)N * 128;
    ushort* W1b = WcT + 128 * 256;
    ushort* W2b = W1b + 128 * 128;
    int* outdeg = (int*)(W2b + 256 * 128);
    int* rp     = outdeg + N;
    int* bb     = rp + (N + 1);
    int* tot    = bb + (nBuk + 1);
    int* M      = tot + nBuk;
    int* ss     = M + nBuk * NCHUNK;

    // ---- fused prep: weight convert + bucket hist + rowptr
    const int rowptrBlocks = (nE + 255) / 256;
    prep_kernel<<<WPREP_BLOCKS + NCHUNK + rowptrBlocks, 256, 0, stream>>>(
        W_conv, W1, W2, WcT, W1b, W2b, src, M, dst, rp, nE, N, nBuk, chunkSz);

    // ---- atomic-free out-degree (bucket sort) ----
    scanA_kernel<<<nBuk, 256, 0, stream>>>(M, tot);
    scanB_kernel<<<1, 512, 0, stream>>>(tot, bb, nBuk);
    scatter_keys_kernel<<<NCHUNK, 256, 0, stream>>>(src, M, bb, ss, nE, nBuk, chunkSz);
    count_kernel<<<nBuk, 256, 0, stream>>>(ss, bb, outdeg, N);

    const int nBlocks128 = (N + 127) / 128;   // 782
    // h1 = bf16[rsqrt(outdeg) * (x @ W_conv)]
    gemm1_kernel<<<nBlocks128, 512, 0, stream>>>(x, WcT, outdeg, h1, N);

    // h2 = bf16[relu(csr_sum(h1) * rsqrt(indeg) + b_conv)]
    gather_kernel<<<(N * 64 + 255) / 256, 256, 0, stream>>>(
        h1, src, rp, b_conv, h2, N);

    // out = relu(h2 @ W1^T + b1) @ W2^T + b2   (single fused kernel)
    gemm23_kernel<<<nBlocks128, 512, 0, stream>>>(h2, W1b, W2b, b1, b2, out, N);
}